// Round 17
// baseline (194.466 us; speedup 1.0000x reference)
//
#include <hip/hip_runtime.h>

typedef unsigned short u16;
typedef unsigned char u8;
typedef signed char s8;
typedef __attribute__((ext_vector_type(8))) short bf16x8;
typedef __attribute__((ext_vector_type(4))) float f32x4;
typedef __attribute__((ext_vector_type(4))) int i32x4;
typedef __attribute__((ext_vector_type(16))) int i32x16;

__device__ __forceinline__ u16 f2bf(float x) {
  unsigned int u = __float_as_uint(x);
  u = u + 0x7FFFu + ((u >> 16) & 1u);
  return (u16)(u >> 16);
}
__device__ __forceinline__ float bf2f(u16 v) {
  return __uint_as_float(((unsigned int)v) << 16);
}

typedef const __attribute__((address_space(1))) void gas_void;
typedef __attribute__((address_space(3))) void las_void;

__device__ __forceinline__ void gld_lds16(const void* g, void* l) {
  __builtin_amdgcn_global_load_lds((gas_void*)g, (las_void*)l, 16, 0, 0);
}

#define CAP 512
#define DU8 8    // window = 32 in dist units (u8 unit = 4)

// ---------------- i8 coarse dist GEMM: 128x128 tile, 4 waves (2x2), wave 64x64 ------
// mfma_i32_32x32x32_i8, 2x2 MFMAs/wave. S(u8) = clamp(round((csq-qh@qc/128-1024)/4)+128)
// BK=128 (128B rows), single 32KB/operand buffer, 2 barriers/K-step.
// DEEP swizzle (verified 0 conflicts): slot = col16 ^ (row&7) ^ ((row>>3)&7);
// inverse on global source (gld_lds dest linear), same XOR on ds_read.
// XCD-bijective block swizzle: 4096 blocks, XCD k owns 8 consecutive row-panels.
__global__ __launch_bounds__(256) void gemm_c8(
    const s8* __restrict__ A0, const s8* __restrict__ B0,
    u8* __restrict__ S, const float* __restrict__ c_sq) {
  __shared__ __align__(16) s8 lA[128 * 128];
  __shared__ __align__(16) s8 lB[128 * 128];
  int tid = threadIdx.x, wave = tid >> 6, lane = tid & 63;
  int id = blockIdx.x;
  int swz = (id & 7) * 512 + (id >> 3);       // bijective (4096 % 8 == 0)
  long bm = (long)(swz >> 6) * 128, bn = (long)(swz & 63) * 128;
  int wm = (wave >> 1) * 64, wn = (wave & 1) * 64;
  int l31 = lane & 31, kg = lane >> 5;
  int srow = wave * 8 + (lane >> 3);

  i32x16 acc[2][2];
#pragma unroll
  for (int i = 0; i < 2; ++i)
#pragma unroll
    for (int j = 0; j < 2; ++j)
#pragma unroll
      for (int r = 0; r < 16; ++r) acc[i][j][r] = 0;

  const s8* ap = A0 + bm * 1024;
  const s8* bp = B0 + bn * 1024;

  for (int k0 = 0; k0 < 1024; k0 += 128) {
    __syncthreads();
#pragma unroll
    for (int c = 0; c < 4; ++c) {
      int sc2 = ((lane & 7) ^ (lane >> 3) ^ ((c * 4 + wave) & 7)) * 16;
      long go = (long)(c * 32 + srow) * 1024 + k0 + sc2;
      int ldoff = c * 4096 + wave * 1024;  // + lane*16 by HW
      gld_lds16(ap + go, lA + ldoff);
      gld_lds16(bp + go, lB + ldoff);
    }
    __syncthreads();
#pragma unroll
    for (int kk = 0; kk < 4; ++kk) {
      i32x4 af[2], bf[2];
#pragma unroll
      for (int i = 0; i < 2; ++i) {
        int ra = wm + i * 32 + l31;
        int rxa = (ra & 7) ^ ((ra >> 3) & 7);
        af[i] = *(const i32x4*)&lA[ra * 128 + ((kk * 2 + kg) ^ rxa) * 16];
        int rb = wn + i * 32 + l31;
        int rxb = (rb & 7) ^ ((rb >> 3) & 7);
        bf[i] = *(const i32x4*)&lB[rb * 128 + ((kk * 2 + kg) ^ rxb) * 16];
      }
#pragma unroll
      for (int i = 0; i < 2; ++i)
#pragma unroll
        for (int j = 0; j < 2; ++j)
          acc[i][j] = __builtin_amdgcn_mfma_i32_32x32x32_i8(af[i], bf[j], acc[i][j], 0, 0, 0);
    }
  }

  // C/D (m74/m101-verified): col=lane&31, row=(r&3)+8*(r>>2)+4*(lane>>5)
#pragma unroll
  for (int i = 0; i < 2; ++i) {
#pragma unroll
    for (int j = 0; j < 2; ++j) {
      long cg = bn + wn + j * 32 + l31;
      float csq = c_sq[cg];
#pragma unroll
      for (int r = 0; r < 16; ++r) {
        long rg = bm + wm + i * 32 + (r & 3) + 8 * (r >> 2) + 4 * kg;
        float v = csq - (float)acc[i][j][r] * 0.0078125f;
        int q = (int)rintf((v - 1024.f) * 0.25f) + 128;
        q = q < 0 ? 0 : (q > 255 ? 255 : q);
        S[rg * 8192 + cg] = (u8)q;
      }
    }
  }
}

// ---------------- bf16 GEMM z_q: 128x64 tile, 4 waves (2x2), wave 64x32 -------------
// C = acc + bf2f(aux0[m*ldc+n]) + aux1[n]; BK=64 (128B rows), 24KB LDS.
__global__ __launch_bounds__(256) void gemm_zq(
    const u16* __restrict__ A0, long lda,
    const u16* __restrict__ B0, long ldb,
    float* __restrict__ C, long ldc, int K,
    const u16* __restrict__ aux0, const float* __restrict__ aux1) {
  __shared__ __align__(16) u16 lA0[128 * 64];
  __shared__ __align__(16) u16 lB0[64 * 64];

  int tid = threadIdx.x;
  int wave = tid >> 6, lane = tid & 63;
  long bm = (long)blockIdx.y * 128, bn = (long)blockIdx.x * 64;
  int wm = (wave >> 1) * 64, wn = (wave & 1) * 32;
  int r15 = lane & 15, kg = lane >> 4;
  int srow = wave * 8 + (lane >> 3);
  int scol = ((lane & 7) ^ (lane >> 3)) * 8;  // u16 units

  f32x4 acc[4][2];
#pragma unroll
  for (int i = 0; i < 4; ++i)
#pragma unroll
    for (int j = 0; j < 2; ++j) acc[i][j] = (f32x4){0.f, 0.f, 0.f, 0.f};

  for (int k0 = 0; k0 < K; k0 += 64) {
    __syncthreads();
#pragma unroll
    for (int c = 0; c < 4; ++c) {
      const u16* g = A0 + (bm + c * 32 + srow) * lda + k0 + scol;
      gld_lds16(g, lA0 + c * 2048 + wave * 512);
    }
#pragma unroll
    for (int c = 0; c < 2; ++c) {
      const u16* g = B0 + (bn + c * 32 + srow) * ldb + k0 + scol;
      gld_lds16(g, lB0 + c * 2048 + wave * 512);
    }
    __syncthreads();

#pragma unroll
    for (int kk = 0; kk < 2; ++kk) {
      int cu = ((kk * 4 + kg) ^ (r15 & 7)) * 8;
      bf16x8 bh[2];
#pragma unroll
      for (int j = 0; j < 2; ++j)
        bh[j] = *(const bf16x8*)&lB0[(wn + j * 16 + r15) * 64 + cu];
#pragma unroll
      for (int i = 0; i < 4; ++i) {
        bf16x8 ah = *(const bf16x8*)&lA0[(wm + i * 16 + r15) * 64 + cu];
#pragma unroll
        for (int j = 0; j < 2; ++j)
          acc[i][j] = __builtin_amdgcn_mfma_f32_16x16x32_bf16(ah, bh[j], acc[i][j], 0, 0, 0);
      }
    }
  }

#pragma unroll
  for (int i = 0; i < 4; ++i) {
    long rg = bm + wm + i * 16 + kg * 4;
#pragma unroll
    for (int j = 0; j < 2; ++j) {
      long cg = bn + wn + j * 16 + r15;
      f32x4 v = acc[i][j];
      float bb = aux1[cg];
#pragma unroll
      for (int r = 0; r < 4; ++r)
        C[(rg + r) * ldc + cg] = v[r] + bf2f(aux0[(rg + r) * ldc + cg]) + bb;
    }
  }
}

// ---------------- prep kernels ----------------
__device__ __forceinline__ int q8(float x) {
  float q = rintf(x * 16.f);
  q = fminf(fmaxf(q, -127.f), 127.f);
  return (int)q;
}

// blocks 0..8191: h -> i8x16; blocks 8192..9215: W -> bf16
__global__ __launch_bounds__(256) void prep_h_w(const float* __restrict__ h,
                                                s8* __restrict__ q0,
                                                const float* __restrict__ W,
                                                u16* __restrict__ Wbf) {
  int b = blockIdx.x;
  if (b < 8192) {
    int i = b * 256 + threadIdx.x;
    float4 v = ((const float4*)h)[i];
    unsigned int w = (unsigned int)((q8(v.x) & 0xFF) | ((q8(v.y) & 0xFF) << 8) |
                                    ((q8(v.z) & 0xFF) << 16) | ((q8(v.w) & 0xFF) << 24));
    ((unsigned int*)q0)[i] = w;
  } else {
    int i = (b - 8192) * 256 + threadIdx.x;
    float4 v = ((const float4*)W)[i];
    ushort4 o;
    o.x = f2bf(v.x); o.y = f2bf(v.y); o.z = f2bf(v.z); o.w = f2bf(v.w);
    ((ushort4*)Wbf)[i] = o;
  }
}

__global__ __launch_bounds__(256) void prep_cb_i8(const float* __restrict__ cb,
                                                  s8* __restrict__ q0,
                                                  float* __restrict__ c_sq) {
  long k = blockIdx.x;
  int t = threadIdx.x, lane = t & 63, wave = t >> 6;
  float4 v = ((const float4*)(cb + k * 1024))[t];
  unsigned int w = (unsigned int)((q8(v.x) & 0xFF) | ((q8(v.y) & 0xFF) << 8) |
                                  ((q8(v.z) & 0xFF) << 16) | ((q8(v.w) & 0xFF) << 24));
  ((unsigned int*)(q0 + k * 1024))[t] = w;
  float ss = v.x * v.x + v.y * v.y + v.z * v.z + v.w * v.w;
#pragma unroll
  for (int o = 32; o; o >>= 1) ss += __shfl_xor(ss, o);
  __shared__ float sc[4];
  if (lane == 0) sc[wave] = ss;
  __syncthreads();
  if (t == 0) c_sq[k] = sc[0] + sc[1] + sc[2] + sc[3];
}

// ---------------- fused scan + refine: one block per row ----------------
// Phase 1: read Sq row (u8), block min, ordered compaction of candidates
// (val <= min+DU8) into LDS. Phase 2: single-pass online-softmax refine with
// exact f32 logits; z_e (bf16 out) + RMSNorm -> x (bf16). Deterministic.
__global__ __launch_bounds__(256) void refine_rms(
    const float* __restrict__ h, const float* __restrict__ cb,
    const float* __restrict__ csq, const u8* __restrict__ Sq,
    const float* __restrict__ scale,
    u16* __restrict__ z_e, u16* __restrict__ x) {
  long m = blockIdx.x;
  int t = threadIdx.x, lane = t & 63, wave = t >> 6;
  __shared__ int cand[CAP];
  __shared__ int smi[4], wsum[4], ncand;
  __shared__ float smf[4], ssum[4], sc[4];
  __shared__ float lacc[4][1024];  // 16KB, per-wave partial z_e (unnormalized)

  // ---- scan phase ----
  const uint4* row4 = (const uint4*)(Sq + m * 8192);
  uint4 va = row4[t], vb = row4[256 + t];   // bytes t*16.. and 4096+t*16..
  unsigned int w[8] = {va.x, va.y, va.z, va.w, vb.x, vb.y, vb.z, vb.w};
  int bmin = 255;
#pragma unroll
  for (int i = 0; i < 8; ++i)
#pragma unroll
    for (int j = 0; j < 4; ++j) {
      int b = (w[i] >> (8 * j)) & 0xFF;
      bmin = b < bmin ? b : bmin;
    }
#pragma unroll
  for (int o = 32; o; o >>= 1) {
    int y = __shfl_xor(bmin, o);
    bmin = y < bmin ? y : bmin;
  }
  if (lane == 0) smi[wave] = bmin;
  __syncthreads();
  bmin = min(min(smi[0], smi[1]), min(smi[2], smi[3]));
  int thr = bmin + DU8;
  int c = 0;
#pragma unroll
  for (int i = 0; i < 8; ++i)
#pragma unroll
    for (int j = 0; j < 4; ++j)
      c += (((w[i] >> (8 * j)) & 0xFF) <= (unsigned)thr);
  int pre = c;
#pragma unroll
  for (int o = 1; o < 64; o <<= 1) {
    int y = __shfl_up(pre, o);
    if (lane >= o) pre += y;
  }
  if (lane == 63) wsum[wave] = pre;
  __syncthreads();
  int base = 0;
#pragma unroll
  for (int wv = 0; wv < 4; ++wv) base += (wv < wave) ? wsum[wv] : 0;
  int pos = base + pre - c;
#pragma unroll
  for (int i = 0; i < 8; ++i)
#pragma unroll
    for (int j = 0; j < 4; ++j) {
      int b = (w[i] >> (8 * j)) & 0xFF;
      if (b <= thr) {
        int col = (i < 4 ? t * 16 : 4096 + t * 16) + (i & 3) * 4 + j;
        if (pos < CAP) cand[pos] = col;
        ++pos;
      }
    }
  if (t == 0) {
    int tot = wsum[0] + wsum[1] + wsum[2] + wsum[3];
    ncand = tot < CAP ? tot : CAP;
  }
  __syncthreads();
  int n = ncand;

  // ---- refine phase: wave w handles candidates j = w, w+4, ...; lane owns 16 dims ----
  const float4* h4 = (const float4*)(h + m * 1024);
  float4 hw[4];
#pragma unroll
  for (int i = 0; i < 4; ++i) hw[i] = h4[lane * 4 + i];

  float mw = -3.0e38f, sw = 0.f;
  float4 a0 = {0.f, 0.f, 0.f, 0.f}, a1 = a0, a2 = a0, a3 = a0;
  for (int j = wave; j < n; j += 4) {
    long k = cand[j];
    const float4* c4 = (const float4*)(cb + k * 1024);
    float4 cv0 = c4[lane * 4 + 0], cv1 = c4[lane * 4 + 1];
    float4 cv2 = c4[lane * 4 + 2], cv3 = c4[lane * 4 + 3];
    float d = hw[0].x * cv0.x + hw[0].y * cv0.y + hw[0].z * cv0.z + hw[0].w * cv0.w +
              hw[1].x * cv1.x + hw[1].y * cv1.y + hw[1].z * cv1.z + hw[1].w * cv1.w +
              hw[2].x * cv2.x + hw[2].y * cv2.y + hw[2].z * cv2.z + hw[2].w * cv2.w +
              hw[3].x * cv3.x + hw[3].y * cv3.y + hw[3].z * cv3.z + hw[3].w * cv3.w;
#pragma unroll
    for (int o = 32; o; o >>= 1) d += __shfl_xor(d, o);
    float lg = 2.f * d - csq[k];
    if (lg > mw) {
      float r = __expf(mw - lg);
      sw *= r;
      a0.x *= r; a0.y *= r; a0.z *= r; a0.w *= r;
      a1.x *= r; a1.y *= r; a1.z *= r; a1.w *= r;
      a2.x *= r; a2.y *= r; a2.z *= r; a2.w *= r;
      a3.x *= r; a3.y *= r; a3.z *= r; a3.w *= r;
      mw = lg;
    }
    float wgt = __expf(lg - mw);
    sw += wgt;
    a0.x += wgt * cv0.x; a0.y += wgt * cv0.y; a0.z += wgt * cv0.z; a0.w += wgt * cv0.w;
    a1.x += wgt * cv1.x; a1.y += wgt * cv1.y; a1.z += wgt * cv1.z; a1.w += wgt * cv1.w;
    a2.x += wgt * cv2.x; a2.y += wgt * cv2.y; a2.z += wgt * cv2.z; a2.w += wgt * cv2.w;
    a3.x += wgt * cv3.x; a3.y += wgt * cv3.y; a3.z += wgt * cv3.z; a3.w += wgt * cv3.w;
  }
  if (lane == 0) { smf[wave] = mw; ssum[wave] = sw; }
  __syncthreads();
  float M = fmaxf(fmaxf(smf[0], smf[1]), fmaxf(smf[2], smf[3]));
  float Stot = ssum[0] * __expf(smf[0] - M) + ssum[1] * __expf(smf[1] - M) +
               ssum[2] * __expf(smf[2] - M) + ssum[3] * __expf(smf[3] - M);
  float rw = __expf(mw - M);
  float* lw = &lacc[wave][lane * 16];
  *(float4*)(lw + 0) = (float4){a0.x * rw, a0.y * rw, a0.z * rw, a0.w * rw};
  *(float4*)(lw + 4) = (float4){a1.x * rw, a1.y * rw, a1.z * rw, a1.w * rw};
  *(float4*)(lw + 8) = (float4){a2.x * rw, a2.y * rw, a2.z * rw, a2.w * rw};
  *(float4*)(lw + 12) = (float4){a3.x * rw, a3.y * rw, a3.z * rw, a3.w * rw};
  __syncthreads();
  float rs = 1.f / Stot;
  float4 p0 = *(const float4*)&lacc[0][t * 4];
  float4 p1 = *(const float4*)&lacc[1][t * 4];
  float4 p2 = *(const float4*)&lacc[2][t * 4];
  float4 p3 = *(const float4*)&lacc[3][t * 4];
  float4 ze;
  ze.x = (p0.x + p1.x + p2.x + p3.x) * rs;
  ze.y = (p0.y + p1.y + p2.y + p3.y) * rs;
  ze.z = (p0.z + p1.z + p2.z + p3.z) * rs;
  ze.w = (p0.w + p1.w + p2.w + p3.w) * rs;
  ushort4 zo;
  zo.x = f2bf(ze.x); zo.y = f2bf(ze.y); zo.z = f2bf(ze.z); zo.w = f2bf(ze.w);
  *(ushort4*)(z_e + m * 1024 + t * 4) = zo;
  float4 hv = h4[t];
  float4 r;
  r.x = hv.x - ze.x; r.y = hv.y - ze.y; r.z = hv.z - ze.z; r.w = hv.w - ze.w;
  float ss = r.x * r.x + r.y * r.y + r.z * r.z + r.w * r.w;
#pragma unroll
  for (int o = 32; o; o >>= 1) ss += __shfl_xor(ss, o);
  if (lane == 0) sc[wave] = ss;
  __syncthreads();
  float tot = sc[0] + sc[1] + sc[2] + sc[3];
  float inv = 1.f / (sqrtf(tot * (1.f / 1024.f)) + 1e-8f);
  float4 s4 = ((const float4*)scale)[t];
  ushort4 o;
  o.x = f2bf(r.x * inv * s4.x); o.y = f2bf(r.y * inv * s4.y);
  o.z = f2bf(r.z * inv * s4.z); o.w = f2bf(r.w * inv * s4.w);
  *(ushort4*)(x + m * 1024 + t * 4) = o;
}

extern "C" void kernel_launch(void* const* d_in, const int* in_sizes, int n_in,
                              void* d_out, int out_size, void* d_ws, size_t ws_size,
                              hipStream_t stream) {
  const float* h = (const float*)d_in[0];
  const float* cb = (const float*)d_in[1];
  const float* scale = (const float*)d_in[2];
  const float* W = (const float*)d_in[3];
  const float* b = (const float*)d_in[4];
  float* out = (float*)d_out;

  // ws layout (~115 MB total)
  char* ws = (char*)d_ws;
  size_t off = 0;
  auto alloc = [&](size_t bytes) -> char* {
    char* p = ws + off;
    off = (off + bytes + 255) & ~(size_t)255;
    return p;
  };
  s8* h8 = (s8*)alloc(8192L * 1024);            // h i8 (x16)
  s8* c8 = (s8*)alloc(8192L * 1024);            // cb i8 (x16)
  u16* Wbf = (u16*)alloc(1024L * 1024 * 2);     // W bf16
  float* c_sq = (float*)alloc(8192L * 4);
  u16* z_e = (u16*)alloc(8192L * 1024 * 2);     // bf16
  u16* x = (u16*)alloc(8192L * 1024 * 2);       // bf16
  u8* Sq = (u8*)alloc(8192L * 8192);            // coarse dist u8: (v-1024)/4 + 128

  prep_h_w<<<9216, 256, 0, stream>>>(h, h8, W, Wbf);
  prep_cb_i8<<<8192, 256, 0, stream>>>(cb, c8, c_sq);

  // coarse dist via 32x32x32 i8 MFMA (deep swizzle + XCD swizzle): Sq u8
  gemm_c8<<<4096, 256, 0, stream>>>(h8, c8, Sq, c_sq);
  // fused scan + single-pass online-softmax refine: z_e (bf16), x (bf16)
  refine_rms<<<8192, 256, 0, stream>>>(h, cb, c_sq, Sq, scale, z_e, x);
  // out = bf2f(z_e) + x @ W^T + b  (128x64 tile)
  gemm_zq<<<dim3(16, 64), 256, 0, stream>>>(x, 1024L, Wbf, 1024L,
                                            out, 1024L, 1024, z_e, b);
}

// Round 18
// 182.481 us; speedup vs baseline: 1.0657x; 1.0657x over previous
//
#include <hip/hip_runtime.h>

typedef unsigned short u16;
typedef unsigned char u8;
typedef signed char s8;
typedef __attribute__((ext_vector_type(8))) short bf16x8;
typedef __attribute__((ext_vector_type(4))) float f32x4;
typedef __attribute__((ext_vector_type(4))) int i32x4;
typedef __attribute__((ext_vector_type(16))) int i32x16;

__device__ __forceinline__ u16 f2bf(float x) {
  unsigned int u = __float_as_uint(x);
  u = u + 0x7FFFu + ((u >> 16) & 1u);
  return (u16)(u >> 16);
}
__device__ __forceinline__ float bf2f(u16 v) {
  return __uint_as_float(((unsigned int)v) << 16);
}

typedef const __attribute__((address_space(1))) void gas_void;
typedef __attribute__((address_space(3))) void las_void;

__device__ __forceinline__ void gld_lds16(const void* g, void* l) {
  __builtin_amdgcn_global_load_lds((gas_void*)g, (las_void*)l, 16, 0, 0);
}

#define CAP 512
#define DU8 8    // window = 32 in dist units (u8 unit = 4)

// ---------------- i8 coarse dist GEMM: 128x128 tile, 4 waves (2x2), wave 64x64 ------
// mfma_i32_32x32x32_i8, 2x2 MFMAs/wave. S(u8) = clamp(round((csq-qh@qc/128-1024)/4)+128)
// BK=128 (128B rows), single 32KB/operand buffer, 2 barriers/K-step.
// DEEP swizzle (verified 0 conflicts): slot = col16 ^ (row&7) ^ ((row>>3)&7);
// inverse on global source (gld_lds dest linear), same XOR on ds_read.
// Default 2-D dispatch (x fastest) — XCD block-swizzle REGRESSED (r17: FETCH 41->245MB).
__global__ __launch_bounds__(256) void gemm_c8(
    const s8* __restrict__ A0, const s8* __restrict__ B0,
    u8* __restrict__ S, const float* __restrict__ c_sq) {
  __shared__ __align__(16) s8 lA[128 * 128];
  __shared__ __align__(16) s8 lB[128 * 128];
  int tid = threadIdx.x, wave = tid >> 6, lane = tid & 63;
  long bm = (long)blockIdx.y * 128, bn = (long)blockIdx.x * 128;
  int wm = (wave >> 1) * 64, wn = (wave & 1) * 64;
  int l31 = lane & 31, kg = lane >> 5;
  int srow = wave * 8 + (lane >> 3);

  i32x16 acc[2][2];
#pragma unroll
  for (int i = 0; i < 2; ++i)
#pragma unroll
    for (int j = 0; j < 2; ++j)
#pragma unroll
      for (int r = 0; r < 16; ++r) acc[i][j][r] = 0;

  const s8* ap = A0 + bm * 1024;
  const s8* bp = B0 + bn * 1024;

  for (int k0 = 0; k0 < 1024; k0 += 128) {
    __syncthreads();
#pragma unroll
    for (int c = 0; c < 4; ++c) {
      int sc2 = ((lane & 7) ^ (lane >> 3) ^ ((c * 4 + wave) & 7)) * 16;
      long go = (long)(c * 32 + srow) * 1024 + k0 + sc2;
      int ldoff = c * 4096 + wave * 1024;  // + lane*16 by HW
      gld_lds16(ap + go, lA + ldoff);
      gld_lds16(bp + go, lB + ldoff);
    }
    __syncthreads();
#pragma unroll
    for (int kk = 0; kk < 4; ++kk) {
      i32x4 af[2], bf[2];
#pragma unroll
      for (int i = 0; i < 2; ++i) {
        int ra = wm + i * 32 + l31;
        int rxa = (ra & 7) ^ ((ra >> 3) & 7);
        af[i] = *(const i32x4*)&lA[ra * 128 + ((kk * 2 + kg) ^ rxa) * 16];
        int rb = wn + i * 32 + l31;
        int rxb = (rb & 7) ^ ((rb >> 3) & 7);
        bf[i] = *(const i32x4*)&lB[rb * 128 + ((kk * 2 + kg) ^ rxb) * 16];
      }
#pragma unroll
      for (int i = 0; i < 2; ++i)
#pragma unroll
        for (int j = 0; j < 2; ++j)
          acc[i][j] = __builtin_amdgcn_mfma_i32_32x32x32_i8(af[i], bf[j], acc[i][j], 0, 0, 0);
    }
  }

  // C/D (m74/m101-verified): col=lane&31, row=(r&3)+8*(r>>2)+4*(lane>>5)
#pragma unroll
  for (int i = 0; i < 2; ++i) {
#pragma unroll
    for (int j = 0; j < 2; ++j) {
      long cg = bn + wn + j * 32 + l31;
      float csq = c_sq[cg];
#pragma unroll
      for (int r = 0; r < 16; ++r) {
        long rg = bm + wm + i * 32 + (r & 3) + 8 * (r >> 2) + 4 * kg;
        float v = csq - (float)acc[i][j][r] * 0.0078125f;
        int q = (int)rintf((v - 1024.f) * 0.25f) + 128;
        q = q < 0 ? 0 : (q > 255 ? 255 : q);
        S[rg * 8192 + cg] = (u8)q;
      }
    }
  }
}

// ---------------- bf16 GEMM z_q: 128x64 tile, 4 waves (2x2), wave 64x32 -------------
// C = acc + bf2f(aux0[m*ldc+n]) + aux1[n]; BK=64 (128B rows), 24KB LDS.
__global__ __launch_bounds__(256) void gemm_zq(
    const u16* __restrict__ A0, long lda,
    const u16* __restrict__ B0, long ldb,
    float* __restrict__ C, long ldc, int K,
    const u16* __restrict__ aux0, const float* __restrict__ aux1) {
  __shared__ __align__(16) u16 lA0[128 * 64];
  __shared__ __align__(16) u16 lB0[64 * 64];

  int tid = threadIdx.x;
  int wave = tid >> 6, lane = tid & 63;
  long bm = (long)blockIdx.y * 128, bn = (long)blockIdx.x * 64;
  int wm = (wave >> 1) * 64, wn = (wave & 1) * 32;
  int r15 = lane & 15, kg = lane >> 4;
  int srow = wave * 8 + (lane >> 3);
  int scol = ((lane & 7) ^ (lane >> 3)) * 8;  // u16 units

  f32x4 acc[4][2];
#pragma unroll
  for (int i = 0; i < 4; ++i)
#pragma unroll
    for (int j = 0; j < 2; ++j) acc[i][j] = (f32x4){0.f, 0.f, 0.f, 0.f};

  for (int k0 = 0; k0 < K; k0 += 64) {
    __syncthreads();
#pragma unroll
    for (int c = 0; c < 4; ++c) {
      const u16* g = A0 + (bm + c * 32 + srow) * lda + k0 + scol;
      gld_lds16(g, lA0 + c * 2048 + wave * 512);
    }
#pragma unroll
    for (int c = 0; c < 2; ++c) {
      const u16* g = B0 + (bn + c * 32 + srow) * ldb + k0 + scol;
      gld_lds16(g, lB0 + c * 2048 + wave * 512);
    }
    __syncthreads();

#pragma unroll
    for (int kk = 0; kk < 2; ++kk) {
      int cu = ((kk * 4 + kg) ^ (r15 & 7)) * 8;
      bf16x8 bh[2];
#pragma unroll
      for (int j = 0; j < 2; ++j)
        bh[j] = *(const bf16x8*)&lB0[(wn + j * 16 + r15) * 64 + cu];
#pragma unroll
      for (int i = 0; i < 4; ++i) {
        bf16x8 ah = *(const bf16x8*)&lA0[(wm + i * 16 + r15) * 64 + cu];
#pragma unroll
        for (int j = 0; j < 2; ++j)
          acc[i][j] = __builtin_amdgcn_mfma_f32_16x16x32_bf16(ah, bh[j], acc[i][j], 0, 0, 0);
      }
    }
  }

#pragma unroll
  for (int i = 0; i < 4; ++i) {
    long rg = bm + wm + i * 16 + kg * 4;
#pragma unroll
    for (int j = 0; j < 2; ++j) {
      long cg = bn + wn + j * 16 + r15;
      f32x4 v = acc[i][j];
      float bb = aux1[cg];
#pragma unroll
      for (int r = 0; r < 4; ++r)
        C[(rg + r) * ldc + cg] = v[r] + bf2f(aux0[(rg + r) * ldc + cg]) + bb;
    }
  }
}

// ---------------- prep kernels ----------------
__device__ __forceinline__ int q8(float x) {
  float q = rintf(x * 16.f);
  q = fminf(fmaxf(q, -127.f), 127.f);
  return (int)q;
}

// blocks 0..8191: h -> i8x16; blocks 8192..9215: W -> bf16
__global__ __launch_bounds__(256) void prep_h_w(const float* __restrict__ h,
                                                s8* __restrict__ q0,
                                                const float* __restrict__ W,
                                                u16* __restrict__ Wbf) {
  int b = blockIdx.x;
  if (b < 8192) {
    int i = b * 256 + threadIdx.x;
    float4 v = ((const float4*)h)[i];
    unsigned int w = (unsigned int)((q8(v.x) & 0xFF) | ((q8(v.y) & 0xFF) << 8) |
                                    ((q8(v.z) & 0xFF) << 16) | ((q8(v.w) & 0xFF) << 24));
    ((unsigned int*)q0)[i] = w;
  } else {
    int i = (b - 8192) * 256 + threadIdx.x;
    float4 v = ((const float4*)W)[i];
    ushort4 o;
    o.x = f2bf(v.x); o.y = f2bf(v.y); o.z = f2bf(v.z); o.w = f2bf(v.w);
    ((ushort4*)Wbf)[i] = o;
  }
}

__global__ __launch_bounds__(256) void prep_cb_i8(const float* __restrict__ cb,
                                                  s8* __restrict__ q0,
                                                  float* __restrict__ c_sq) {
  long k = blockIdx.x;
  int t = threadIdx.x, lane = t & 63, wave = t >> 6;
  float4 v = ((const float4*)(cb + k * 1024))[t];
  unsigned int w = (unsigned int)((q8(v.x) & 0xFF) | ((q8(v.y) & 0xFF) << 8) |
                                  ((q8(v.z) & 0xFF) << 16) | ((q8(v.w) & 0xFF) << 24));
  ((unsigned int*)(q0 + k * 1024))[t] = w;
  float ss = v.x * v.x + v.y * v.y + v.z * v.z + v.w * v.w;
#pragma unroll
  for (int o = 32; o; o >>= 1) ss += __shfl_xor(ss, o);
  __shared__ float sc[4];
  if (lane == 0) sc[wave] = ss;
  __syncthreads();
  if (t == 0) c_sq[k] = sc[0] + sc[1] + sc[2] + sc[3];
}

// ---------------- fused scan + refine: one block per row ----------------
// Phase 1: read Sq row (u8), block min, ordered compaction of candidates
// (val <= min+DU8) into LDS. Phase 2: single-pass online-softmax refine with
// exact f32 logits; z_e (bf16 out) + RMSNorm -> x (bf16). Deterministic.
__global__ __launch_bounds__(256) void refine_rms(
    const float* __restrict__ h, const float* __restrict__ cb,
    const float* __restrict__ csq, const u8* __restrict__ Sq,
    const float* __restrict__ scale,
    u16* __restrict__ z_e, u16* __restrict__ x) {
  long m = blockIdx.x;
  int t = threadIdx.x, lane = t & 63, wave = t >> 6;
  __shared__ int cand[CAP];
  __shared__ int smi[4], wsum[4], ncand;
  __shared__ float smf[4], ssum[4], sc[4];
  __shared__ float lacc[4][1024];  // 16KB, per-wave partial z_e (unnormalized)

  // ---- scan phase ----
  const uint4* row4 = (const uint4*)(Sq + m * 8192);
  uint4 va = row4[t], vb = row4[256 + t];   // bytes t*16.. and 4096+t*16..
  unsigned int w[8] = {va.x, va.y, va.z, va.w, vb.x, vb.y, vb.z, vb.w};
  int bmin = 255;
#pragma unroll
  for (int i = 0; i < 8; ++i)
#pragma unroll
    for (int j = 0; j < 4; ++j) {
      int b = (w[i] >> (8 * j)) & 0xFF;
      bmin = b < bmin ? b : bmin;
    }
#pragma unroll
  for (int o = 32; o; o >>= 1) {
    int y = __shfl_xor(bmin, o);
    bmin = y < bmin ? y : bmin;
  }
  if (lane == 0) smi[wave] = bmin;
  __syncthreads();
  bmin = min(min(smi[0], smi[1]), min(smi[2], smi[3]));
  int thr = bmin + DU8;
  int c = 0;
#pragma unroll
  for (int i = 0; i < 8; ++i)
#pragma unroll
    for (int j = 0; j < 4; ++j)
      c += (((w[i] >> (8 * j)) & 0xFF) <= (unsigned)thr);
  int pre = c;
#pragma unroll
  for (int o = 1; o < 64; o <<= 1) {
    int y = __shfl_up(pre, o);
    if (lane >= o) pre += y;
  }
  if (lane == 63) wsum[wave] = pre;
  __syncthreads();
  int base = 0;
#pragma unroll
  for (int wv = 0; wv < 4; ++wv) base += (wv < wave) ? wsum[wv] : 0;
  int pos = base + pre - c;
#pragma unroll
  for (int i = 0; i < 8; ++i)
#pragma unroll
    for (int j = 0; j < 4; ++j) {
      int b = (w[i] >> (8 * j)) & 0xFF;
      if (b <= thr) {
        int col = (i < 4 ? t * 16 : 4096 + t * 16) + (i & 3) * 4 + j;
        if (pos < CAP) cand[pos] = col;
        ++pos;
      }
    }
  if (t == 0) {
    int tot = wsum[0] + wsum[1] + wsum[2] + wsum[3];
    ncand = tot < CAP ? tot : CAP;
  }
  __syncthreads();
  int n = ncand;

  // ---- refine phase: wave w handles candidates j = w, w+4, ...; lane owns 16 dims ----
  const float4* h4 = (const float4*)(h + m * 1024);
  float4 hw[4];
#pragma unroll
  for (int i = 0; i < 4; ++i) hw[i] = h4[lane * 4 + i];

  float mw = -3.0e38f, sw = 0.f;
  float4 a0 = {0.f, 0.f, 0.f, 0.f}, a1 = a0, a2 = a0, a3 = a0;
  for (int j = wave; j < n; j += 4) {
    long k = cand[j];
    const float4* c4 = (const float4*)(cb + k * 1024);
    float4 cv0 = c4[lane * 4 + 0], cv1 = c4[lane * 4 + 1];
    float4 cv2 = c4[lane * 4 + 2], cv3 = c4[lane * 4 + 3];
    float d = hw[0].x * cv0.x + hw[0].y * cv0.y + hw[0].z * cv0.z + hw[0].w * cv0.w +
              hw[1].x * cv1.x + hw[1].y * cv1.y + hw[1].z * cv1.z + hw[1].w * cv1.w +
              hw[2].x * cv2.x + hw[2].y * cv2.y + hw[2].z * cv2.z + hw[2].w * cv2.w +
              hw[3].x * cv3.x + hw[3].y * cv3.y + hw[3].z * cv3.z + hw[3].w * cv3.w;
#pragma unroll
    for (int o = 32; o; o >>= 1) d += __shfl_xor(d, o);
    float lg = 2.f * d - csq[k];
    if (lg > mw) {
      float r = __expf(mw - lg);
      sw *= r;
      a0.x *= r; a0.y *= r; a0.z *= r; a0.w *= r;
      a1.x *= r; a1.y *= r; a1.z *= r; a1.w *= r;
      a2.x *= r; a2.y *= r; a2.z *= r; a2.w *= r;
      a3.x *= r; a3.y *= r; a3.z *= r; a3.w *= r;
      mw = lg;
    }
    float wgt = __expf(lg - mw);
    sw += wgt;
    a0.x += wgt * cv0.x; a0.y += wgt * cv0.y; a0.z += wgt * cv0.z; a0.w += wgt * cv0.w;
    a1.x += wgt * cv1.x; a1.y += wgt * cv1.y; a1.z += wgt * cv1.z; a1.w += wgt * cv1.w;
    a2.x += wgt * cv2.x; a2.y += wgt * cv2.y; a2.z += wgt * cv2.z; a2.w += wgt * cv2.w;
    a3.x += wgt * cv3.x; a3.y += wgt * cv3.y; a3.z += wgt * cv3.z; a3.w += wgt * cv3.w;
  }
  if (lane == 0) { smf[wave] = mw; ssum[wave] = sw; }
  __syncthreads();
  float M = fmaxf(fmaxf(smf[0], smf[1]), fmaxf(smf[2], smf[3]));
  float Stot = ssum[0] * __expf(smf[0] - M) + ssum[1] * __expf(smf[1] - M) +
               ssum[2] * __expf(smf[2] - M) + ssum[3] * __expf(smf[3] - M);
  float rw = __expf(mw - M);
  float* lw = &lacc[wave][lane * 16];
  *(float4*)(lw + 0) = (float4){a0.x * rw, a0.y * rw, a0.z * rw, a0.w * rw};
  *(float4*)(lw + 4) = (float4){a1.x * rw, a1.y * rw, a1.z * rw, a1.w * rw};
  *(float4*)(lw + 8) = (float4){a2.x * rw, a2.y * rw, a2.z * rw, a2.w * rw};
  *(float4*)(lw + 12) = (float4){a3.x * rw, a3.y * rw, a3.z * rw, a3.w * rw};
  __syncthreads();
  float rs = 1.f / Stot;
  float4 p0 = *(const float4*)&lacc[0][t * 4];
  float4 p1 = *(const float4*)&lacc[1][t * 4];
  float4 p2 = *(const float4*)&lacc[2][t * 4];
  float4 p3 = *(const float4*)&lacc[3][t * 4];
  float4 ze;
  ze.x = (p0.x + p1.x + p2.x + p3.x) * rs;
  ze.y = (p0.y + p1.y + p2.y + p3.y) * rs;
  ze.z = (p0.z + p1.z + p2.z + p3.z) * rs;
  ze.w = (p0.w + p1.w + p2.w + p3.w) * rs;
  ushort4 zo;
  zo.x = f2bf(ze.x); zo.y = f2bf(ze.y); zo.z = f2bf(ze.z); zo.w = f2bf(ze.w);
  *(ushort4*)(z_e + m * 1024 + t * 4) = zo;
  float4 hv = h4[t];
  float4 r;
  r.x = hv.x - ze.x; r.y = hv.y - ze.y; r.z = hv.z - ze.z; r.w = hv.w - ze.w;
  float ss = r.x * r.x + r.y * r.y + r.z * r.z + r.w * r.w;
#pragma unroll
  for (int o = 32; o; o >>= 1) ss += __shfl_xor(ss, o);
  if (lane == 0) sc[wave] = ss;
  __syncthreads();
  float tot = sc[0] + sc[1] + sc[2] + sc[3];
  float inv = 1.f / (sqrtf(tot * (1.f / 1024.f)) + 1e-8f);
  float4 s4 = ((const float4*)scale)[t];
  ushort4 o;
  o.x = f2bf(r.x * inv * s4.x); o.y = f2bf(r.y * inv * s4.y);
  o.z = f2bf(r.z * inv * s4.z); o.w = f2bf(r.w * inv * s4.w);
  *(ushort4*)(x + m * 1024 + t * 4) = o;
}

extern "C" void kernel_launch(void* const* d_in, const int* in_sizes, int n_in,
                              void* d_out, int out_size, void* d_ws, size_t ws_size,
                              hipStream_t stream) {
  const float* h = (const float*)d_in[0];
  const float* cb = (const float*)d_in[1];
  const float* scale = (const float*)d_in[2];
  const float* W = (const float*)d_in[3];
  const float* b = (const float*)d_in[4];
  float* out = (float*)d_out;

  // ws layout (~115 MB total)
  char* ws = (char*)d_ws;
  size_t off = 0;
  auto alloc = [&](size_t bytes) -> char* {
    char* p = ws + off;
    off = (off + bytes + 255) & ~(size_t)255;
    return p;
  };
  s8* h8 = (s8*)alloc(8192L * 1024);            // h i8 (x16)
  s8* c8 = (s8*)alloc(8192L * 1024);            // cb i8 (x16)
  u16* Wbf = (u16*)alloc(1024L * 1024 * 2);     // W bf16
  float* c_sq = (float*)alloc(8192L * 4);
  u16* z_e = (u16*)alloc(8192L * 1024 * 2);     // bf16
  u16* x = (u16*)alloc(8192L * 1024 * 2);       // bf16
  u8* Sq = (u8*)alloc(8192L * 8192);            // coarse dist u8: (v-1024)/4 + 128

  prep_h_w<<<9216, 256, 0, stream>>>(h, h8, W, Wbf);
  prep_cb_i8<<<8192, 256, 0, stream>>>(cb, c8, c_sq);

  // coarse dist via 32x32x32 i8 MFMA (deep swizzle, default dispatch): Sq u8
  gemm_c8<<<dim3(64, 64), 256, 0, stream>>>(h8, c8, Sq, c_sq);
  // fused scan + single-pass online-softmax refine: z_e (bf16), x (bf16)
  refine_rms<<<8192, 256, 0, stream>>>(h, cb, c_sq, Sq, scale, z_e, x);
  // out = bf2f(z_e) + x @ W^T + b  (128x64 tile)
  gemm_zq<<<dim3(16, 64), 256, 0, stream>>>(x, 1024L, Wbf, 1024L,
                                            out, 1024L, 1024, z_e, b);
}